// Round 6
// baseline (733.288 us; speedup 1.0000x reference)
//
#include <hip/hip_runtime.h>
#include <hip/hip_bf16.h>
#include <hip/hip_cooperative_groups.h>
#include <math.h>

namespace cg = cooperative_groups;

#define IN_DIM 128
#define OUT_DIM 64
#define NHEAD 4
#define HDIM 16
#define TEMP_INV 2.0f
#define NEG_SLOPE 0.01f
#define GR 64            // rows per gemm block

__device__ inline float lrelu(float x) { return x >= 0.f ? x : NEG_SLOPE * x; }

__device__ inline void atomicMaxF(float* addr, float v) {
    if (v >= 0.f) atomicMax((int*)addr, __float_as_int(v));
    else          atomicMin((unsigned int*)addr, __float_as_uint(v));
}

__device__ inline float bf16_to_f(unsigned short u) {
    return __uint_as_float(((unsigned)u) << 16);
}

// ---------------------------------------------------------------------------
// K_prep (cooperative, 512 blocks x 256): mask->Wp, mAD init, deg zero,
// hist, 3-phase scan, CSR fill. Replaces 7 dispatches + memset.
// ---------------------------------------------------------------------------
__global__ void k_prep(const float* __restrict__ logits, const float* __restrict__ gumbel,
                       const float* __restrict__ W, const int* __restrict__ src,
                       const int* __restrict__ dst, float* __restrict__ Wp,
                       unsigned* __restrict__ mAD_bits, int* __restrict__ deg,
                       int* __restrict__ cursor, int* __restrict__ bsum,
                       int* __restrict__ csr, int N, int E, int nb) {
    cg::grid_group grid = cg::this_grid();
    __shared__ float shm[IN_DIM];
    __shared__ int wsum[4];
    int t = threadIdx.x;
    int gid = blockIdx.x * blockDim.x + t;
    int gstride = gridDim.x * blockDim.x;

    // ---- phase 0: zero deg (all blocks); mask + Wp + mAD init (block 0) ----
    for (int i = gid; i < N; i += gstride) deg[i] = 0;
    if (blockIdx.x == 0) {
        if (t < 8) mAD_bits[t] = 0xFF800000u;   // -inf
        float v = 0.f;
        if (t < IN_DIM) { v = (logits[t] + gumbel[t]) * TEMP_INV; shm[t] = v; }
        __syncthreads();
        float mx = -INFINITY;
        for (int i = 0; i < IN_DIM; ++i) mx = fmaxf(mx, shm[i]);
        float e = __expf(v - mx);
        __syncthreads();
        if (t < IN_DIM) shm[t] = e;
        __syncthreads();
        float sum = 0.f;
        for (int i = 0; i < IN_DIM; ++i) sum += shm[i];
        __syncthreads();
        if (t < IN_DIM) shm[t] = e / sum;       // mask
        __syncthreads();
        for (int idx = t; idx < IN_DIM * OUT_DIM; idx += blockDim.x)
            Wp[idx] = shm[idx >> 6] * W[idx];
    }
    grid.sync();

    // ---- phase 1: histogram of dst ----
    for (int e = gid; e < E; e += gstride) atomicAdd(&deg[dst[e]], 1);
    grid.sync();

    // ---- phase 2a: per-block scan (1024 elems per block, blocks < nb) ----
    if (blockIdx.x < nb) {
        int lane = t & 63, wid = t >> 6;
        int i0 = blockIdx.x * 1024 + t * 4;
        int a0 = (i0 + 0 < N) ? deg[i0 + 0] : 0;
        int a1 = (i0 + 1 < N) ? deg[i0 + 1] : 0;
        int a2 = (i0 + 2 < N) ? deg[i0 + 2] : 0;
        int a3 = (i0 + 3 < N) ? deg[i0 + 3] : 0;
        int s = a0 + a1 + a2 + a3;
        int x = s;
        #pragma unroll
        for (int off = 1; off < 64; off <<= 1) {
            int y = __shfl_up(x, off, 64);
            if (lane >= off) x += y;
        }
        if (lane == 63) wsum[wid] = x;
        __syncthreads();
        int wbase = 0;
        for (int w = 0; w < wid; ++w) wbase += wsum[w];
        int excl = wbase + x - s;
        if (i0 + 0 < N) cursor[i0 + 0] = excl;
        if (i0 + 1 < N) cursor[i0 + 1] = excl + a0;
        if (i0 + 2 < N) cursor[i0 + 2] = excl + a0 + a1;
        if (i0 + 3 < N) cursor[i0 + 3] = excl + a0 + a1 + a2;
        if (t == 255) bsum[blockIdx.x] = wbase + x;
    }
    grid.sync();

    // ---- phase 2b: scan block sums (nb <= 256), block 0 ----
    if (blockIdx.x == 0) {
        int lane = t & 63, wid = t >> 6;
        int v = (t < nb) ? bsum[t] : 0;
        int x = v;
        #pragma unroll
        for (int off = 1; off < 64; off <<= 1) {
            int y = __shfl_up(x, off, 64);
            if (lane >= off) x += y;
        }
        __syncthreads();                 // wsum reused; ensure 2a writes done in-block
        if (lane == 63) wsum[wid] = x;
        __syncthreads();
        int wbase = 0;
        for (int w = 0; w < wid; ++w) wbase += wsum[w];
        if (t < nb) bsum[t] = wbase + x - v;   // exclusive
    }
    grid.sync();

    // ---- phase 2c: add block bases ----
    for (int i = gid; i < N; i += gstride) cursor[i] += bsum[i >> 10];
    grid.sync();

    // ---- phase 3: fill CSR ----
    for (int e = gid; e < E; e += gstride) {
        int d = dst[e];
        int pos = atomicAdd(&cursor[d], 1);
        csr[pos] = src[e];
    }
}

// ---------------------------------------------------------------------------
// K_gemm: LDS-tiled h = feat @ Wp; h stored bf16; epilogue asrc/adst + mAD max.
// 512 threads, 64 rows/block; wave w computes rows w*8..w*8+7, lane = col.
// ---------------------------------------------------------------------------
__global__ __launch_bounds__(512) void k_gemm(
        const float* __restrict__ feat, const float* __restrict__ Wp,
        const float* __restrict__ attn_w, unsigned short* __restrict__ h16,
        float* __restrict__ asrc, float* __restrict__ adst,
        float* __restrict__ mAD, int N) {
    __shared__ float sW[IN_DIM * OUT_DIM];   // 32 KB
    __shared__ float sF[GR * IN_DIM];        // 32 KB
    __shared__ float sA[NHEAD * 2 * HDIM];   // 512 B
    __shared__ float redA[8][NHEAD], redD[8][NHEAD];

    int t = threadIdx.x;
    int row0 = blockIdx.x * GR;

    const float4* Wp4 = (const float4*)Wp;
    float4* sW4 = (float4*)sW;
    for (int i = t; i < IN_DIM * OUT_DIM / 4; i += 512) sW4[i] = Wp4[i];
    if (t < NHEAD * 2 * HDIM) sA[t] = attn_w[t];

    const float4* feat4 = (const float4*)feat;
    float4* sF4 = (float4*)sF;
    int totF4 = N * (IN_DIM / 4);
    #pragma unroll
    for (int i = t; i < GR * IN_DIM / 4; i += 512) {
        int g = row0 * (IN_DIM / 4) + i;
        sF4[i] = (g < totF4) ? feat4[g] : make_float4(0.f, 0.f, 0.f, 0.f);
    }
    __syncthreads();

    int wave = t >> 6, lane = t & 63;
    int head = lane >> 4, d = lane & 15;
    float aw_s = sA[head * 2 * HDIM + d];
    float aw_d = sA[head * 2 * HDIM + HDIM + d];

    float acc[8] = {0.f, 0.f, 0.f, 0.f, 0.f, 0.f, 0.f, 0.f};
    for (int k4 = 0; k4 < IN_DIM / 4; ++k4) {
        float w0 = sW[(k4 * 4 + 0) * OUT_DIM + lane];
        float w1 = sW[(k4 * 4 + 1) * OUT_DIM + lane];
        float w2 = sW[(k4 * 4 + 2) * OUT_DIM + lane];
        float w3 = sW[(k4 * 4 + 3) * OUT_DIM + lane];
        #pragma unroll
        for (int j = 0; j < 8; ++j) {
            float4 a = sF4[(wave * 8 + j) * (IN_DIM / 4) + k4];   // uniform -> broadcast
            acc[j] = fmaf(a.x, w0, fmaf(a.y, w1, fmaf(a.z, w2, fmaf(a.w, w3, acc[j]))));
        }
    }

    float mAloc = -INFINITY, mDloc = -INFINITY;
    #pragma unroll
    for (int j = 0; j < 8; ++j) {
        int row = row0 + wave * 8 + j;
        bool ok = row < N;
        unsigned bits = __float_as_uint(acc[j]);
        unsigned r16 = (bits + 0x7FFFu + ((bits >> 16) & 1u)) >> 16;   // RNE bf16
        if (ok) h16[(size_t)row * OUT_DIM + lane] = (unsigned short)r16;
        float v1 = acc[j] * aw_s;
        float v2 = acc[j] * aw_d;
        #pragma unroll
        for (int off = 1; off < HDIM; off <<= 1) {
            v1 += __shfl_xor(v1, off, 64);
            v2 += __shfl_xor(v2, off, 64);
        }
        if (ok) {
            if (d == 0) {
                asrc[(size_t)row * NHEAD + head] = v1;
                adst[(size_t)row * NHEAD + head] = v2;
            }
            mAloc = fmaxf(mAloc, v1);
            mDloc = fmaxf(mDloc, v2);
        }
    }
    if (d == 0) { redA[wave][head] = mAloc; redD[wave][head] = mDloc; }
    __syncthreads();
    if (t < NHEAD) {
        float a = redA[0][t], dd = redD[0][t];
        for (int w = 1; w < 8; ++w) { a = fmaxf(a, redA[w][t]); dd = fmaxf(dd, redD[w][t]); }
        atomicMaxF(&mAD[t], a);
        atomicMaxF(&mAD[NHEAD + t], dd);
    }
}

// ---------------------------------------------------------------------------
// K_fused: per-dst-node softmax + weighted bf16-h gather, global shift B.
// One wave per node; lane = output column; 4-way unrolled.
// ---------------------------------------------------------------------------
__global__ void k_fused(const int* __restrict__ cursor, const int* __restrict__ csr,
                        const float* __restrict__ asrc, const float* __restrict__ adst,
                        const float* __restrict__ mAD, const unsigned short* __restrict__ h16,
                        float* __restrict__ out, int nN) {
    int node = blockIdx.x * 4 + (threadIdx.x >> 6);
    if (node >= nN) return;
    int lane = threadIdx.x & 63;
    int head = lane >> 4;
    int start = (node == 0) ? 0 : cursor[node - 1];
    int end = cursor[node];
    float ad = adst[node * 4 + head];
    float B = lrelu(mAD[head] + mAD[4 + head]);
    float acc0 = 0.f, acc1 = 0.f, acc2 = 0.f, acc3 = 0.f;
    float l0 = 0.f, l1 = 0.f, l2 = 0.f, l3 = 0.f;
    for (int e = start; e < end; e += 4) {
        int n = end - e;
        int e1 = n > 1 ? e + 1 : e;
        int e2 = n > 2 ? e + 2 : e;
        int e3 = n > 3 ? e + 3 : e;
        int s0 = csr[e], s1 = csr[e1], s2 = csr[e2], s3 = csr[e3];
        float av0 = asrc[s0 * 4 + head];
        float av1 = asrc[s1 * 4 + head];
        float av2 = asrc[s2 * 4 + head];
        float av3 = asrc[s3 * 4 + head];
        float hv0 = bf16_to_f(h16[(size_t)s0 * OUT_DIM + lane]);
        float hv1 = bf16_to_f(h16[(size_t)s1 * OUT_DIM + lane]);
        float hv2 = bf16_to_f(h16[(size_t)s2 * OUT_DIM + lane]);
        float hv3 = bf16_to_f(h16[(size_t)s3 * OUT_DIM + lane]);
        float p0 = __expf(lrelu(av0 + ad) - B);
        float p1 = __expf(lrelu(av1 + ad) - B);
        float p2 = __expf(lrelu(av2 + ad) - B);
        float p3 = __expf(lrelu(av3 + ad) - B);
        p1 = (n > 1) ? p1 : 0.f;
        p2 = (n > 2) ? p2 : 0.f;
        p3 = (n > 3) ? p3 : 0.f;
        acc0 += p0 * hv0; l0 += p0;
        acc1 += p1 * hv1; l1 += p1;
        acc2 += p2 * hv2; l2 += p2;
        acc3 += p3 * hv3; l3 += p3;
    }
    float accs = (acc0 + acc1) + (acc2 + acc3);
    float ls = (l0 + l1) + (l2 + l3);
    out[(size_t)node * OUT_DIM + lane] = (end > start) ? accs / ls : 0.f;
}

extern "C" void kernel_launch(void* const* d_in, const int* in_sizes, int n_in,
                              void* d_out, int out_size, void* d_ws, size_t ws_size,
                              hipStream_t stream) {
    const float* feat   = (const float*)d_in[0];
    const int*   src    = (const int*)  d_in[1];
    const int*   dst    = (const int*)  d_in[2];
    const float* gumbel = (const float*)d_in[3];
    const float* logits = (const float*)d_in[4];
    const float* W      = (const float*)d_in[5];
    const float* attn_w = (const float*)d_in[6];
    float* out = (float*)d_out;

    int N = in_sizes[0] / IN_DIM;
    int E = in_sizes[1];
    int nb = (N + 1023) / 1024;

    float* ws     = (float*)d_ws;
    float* Wp     = ws;                                  // 8192
    float* asrc   = Wp + IN_DIM * OUT_DIM;               // N*4
    float* adst   = asrc + (size_t)N * NHEAD;            // N*4
    float* mAD    = adst + (size_t)N * NHEAD;            // 8
    int*   deg    = (int*)(mAD + 8);                     // N
    int*   cursor = deg + N;                             // N
    int*   bsum   = cursor + N;                          // 256
    int*   csr    = bsum + 256;                          // E
    unsigned short* h16 = (unsigned short*)(csr + E);    // N*64 bf16

    // --- K_prep (cooperative): mask/Wp, mAD init, deg zero, hist, scan, fill ---
    {
        const float* a_logits = logits; const float* a_gumbel = gumbel;
        const float* a_W = W; const int* a_src = src; const int* a_dst = dst;
        float* a_Wp = Wp; unsigned* a_mAD = (unsigned*)mAD;
        int* a_deg = deg; int* a_cursor = cursor; int* a_bsum = bsum; int* a_csr = csr;
        int a_N = N, a_E = E, a_nb = nb;
        void* args[] = {&a_logits, &a_gumbel, &a_W, &a_src, &a_dst, &a_Wp, &a_mAD,
                        &a_deg, &a_cursor, &a_bsum, &a_csr, &a_N, &a_E, &a_nb};
        hipLaunchCooperativeKernel((const void*)k_prep, dim3(512), dim3(256),
                                   args, 0, stream);
    }
    k_gemm<<<(N + GR - 1) / GR, 512, 0, stream>>>(feat, Wp, attn_w, h16, asrc, adst, mAD, N);
    k_fused<<<(N + 3) / 4, 256, 0, stream>>>(cursor, csr, asrc, adst, mAD, h16, out, N);
}

// Round 7
// 445.659 us; speedup vs baseline: 1.6454x; 1.6454x over previous
//
#include <hip/hip_runtime.h>
#include <hip/hip_bf16.h>
#include <math.h>

#define IN_DIM 128
#define OUT_DIM 64
#define NHEAD 4
#define HDIM 16
#define TEMP_INV 2.0f
#define NEG_SLOPE 0.01f
#define GR 64            // rows per gemm block

__device__ inline float lrelu(float x) { return x >= 0.f ? x : NEG_SLOPE * x; }

// mAD is initialized by memset(0xFF): 0xFFFFFFFF acts as -inf for both branches
// (int max vs -1; uint min vs UINT_MAX).
__device__ inline void atomicMaxF(float* addr, float v) {
    if (v >= 0.f) atomicMax((int*)addr, __float_as_int(v));
    else          atomicMin((unsigned int*)addr, __float_as_uint(v));
}

__device__ inline float bf16_to_f(unsigned short u) {
    return __uint_as_float(((unsigned)u) << 16);
}

// K1: histogram of dst -> deg
__global__ void k_hist(const int* __restrict__ dst, int* __restrict__ deg, int nE) {
    int e = blockIdx.x * blockDim.x + threadIdx.x;
    if (e < nE) atomicAdd(&deg[dst[e]], 1);
}

// K2a: per-block scan (256 thr x 4 elem = 1024/block); cursor = block-LOCAL excl scan
__global__ void k_scan1(const int* __restrict__ deg, int* __restrict__ cursor,
                        int* __restrict__ bsum, int n) {
    __shared__ int wsum[4];
    int t = threadIdx.x, lane = t & 63, wid = t >> 6;
    int i0 = blockIdx.x * 1024 + t * 4;
    int a0 = (i0 + 0 < n) ? deg[i0 + 0] : 0;
    int a1 = (i0 + 1 < n) ? deg[i0 + 1] : 0;
    int a2 = (i0 + 2 < n) ? deg[i0 + 2] : 0;
    int a3 = (i0 + 3 < n) ? deg[i0 + 3] : 0;
    int s = a0 + a1 + a2 + a3;
    int x = s;
    #pragma unroll
    for (int off = 1; off < 64; off <<= 1) {
        int y = __shfl_up(x, off, 64);
        if (lane >= off) x += y;
    }
    if (lane == 63) wsum[wid] = x;
    __syncthreads();
    int wbase = 0;
    for (int w = 0; w < wid; ++w) wbase += wsum[w];
    int excl = wbase + x - s;
    if (i0 + 0 < n) cursor[i0 + 0] = excl;
    if (i0 + 1 < n) cursor[i0 + 1] = excl + a0;
    if (i0 + 2 < n) cursor[i0 + 2] = excl + a0 + a1;
    if (i0 + 3 < n) cursor[i0 + 3] = excl + a0 + a1 + a2;
    if (t == 255) bsum[blockIdx.x] = wbase + x;   // block total
}

// K2b: exclusive scan of block sums (nb <= 256), single block
__global__ void k_scan2(int* __restrict__ bsum, int nb) {
    __shared__ int wsum[4];
    int t = threadIdx.x, lane = t & 63, wid = t >> 6;
    int v = (t < nb) ? bsum[t] : 0;
    int x = v;
    #pragma unroll
    for (int off = 1; off < 64; off <<= 1) {
        int y = __shfl_up(x, off, 64);
        if (lane >= off) x += y;
    }
    if (lane == 63) wsum[wid] = x;
    __syncthreads();
    int wbase = 0;
    for (int w = 0; w < wid; ++w) wbase += wsum[w];
    if (t < nb) bsum[t] = wbase + x - v;          // exclusive
}

// K3: fill CSR. Global position = local cursor bump + block base (scan3 folded in).
__global__ void k_fill(const int* __restrict__ src, const int* __restrict__ dst,
                       int* __restrict__ cursor, const int* __restrict__ bsum,
                       int* __restrict__ csr, int nE) {
    int e = blockIdx.x * blockDim.x + threadIdx.x;
    if (e >= nE) return;
    int d = dst[e];
    int pos = atomicAdd(&cursor[d], 1) + bsum[d >> 10];
    csr[pos] = src[e];
}

// K4: h = feat @ (diag(mask)W), mask softmax recomputed per block (W is L2-resident).
// h stored bf16. Epilogue: asrc/adst per-head dots + global-max into mAD.
// 512 threads, 64 rows/block; wave w computes rows w*8..w*8+7, lane = col.
__global__ __launch_bounds__(512) void k_gemm(
        const float* __restrict__ feat, const float* __restrict__ W,
        const float* __restrict__ logits, const float* __restrict__ gumbel,
        const float* __restrict__ attn_w, unsigned short* __restrict__ h16,
        float* __restrict__ asrc, float* __restrict__ adst,
        float* __restrict__ mAD, int N) {
    __shared__ float sW[IN_DIM * OUT_DIM];   // 32 KB (masked W)
    __shared__ float sF[GR * IN_DIM];        // 32 KB
    __shared__ float sMask[IN_DIM];
    __shared__ float sA[NHEAD * 2 * HDIM];   // 512 B
    __shared__ float redA[8][NHEAD], redD[8][NHEAD];

    int t = threadIdx.x;
    int row0 = blockIdx.x * GR;

    // ---- mask = softmax((logits+gumbel)/TEMP), in-block ----
    if (t < IN_DIM) sMask[t] = (logits[t] + gumbel[t]) * TEMP_INV;
    if (t < NHEAD * 2 * HDIM) sA[t] = attn_w[t];
    __syncthreads();
    float v = 0.f, ex = 0.f;
    if (t < IN_DIM) {
        v = sMask[t];
        float mx = -INFINITY;
        for (int i = 0; i < IN_DIM; ++i) mx = fmaxf(mx, sMask[i]);
        ex = __expf(v - mx);
    }
    __syncthreads();
    if (t < IN_DIM) sMask[t] = ex;
    __syncthreads();
    float sum = 0.f;
    if (t < IN_DIM) for (int i = 0; i < IN_DIM; ++i) sum += sMask[i];
    __syncthreads();
    if (t < IN_DIM) sMask[t] = ex / sum;
    __syncthreads();

    // ---- stage masked W and feat tile ----
    const float4* W4 = (const float4*)W;
    float4* sW4 = (float4*)sW;
    for (int i = t; i < IN_DIM * OUT_DIM / 4; i += 512) {
        float4 w = W4[i];
        float m = sMask[i >> 4];              // 4 elems of a float4 share a row (64%4==0)
        sW4[i] = make_float4(w.x * m, w.y * m, w.z * m, w.w * m);
    }
    const float4* feat4 = (const float4*)feat;
    float4* sF4 = (float4*)sF;
    int totF4 = N * (IN_DIM / 4);
    for (int i = t; i < GR * IN_DIM / 4; i += 512) {
        int g = row0 * (IN_DIM / 4) + i;
        sF4[i] = (g < totF4) ? feat4[g] : make_float4(0.f, 0.f, 0.f, 0.f);
    }
    __syncthreads();

    int wave = t >> 6, lane = t & 63;
    int head = lane >> 4, d = lane & 15;
    float aw_s = sA[head * 2 * HDIM + d];
    float aw_d = sA[head * 2 * HDIM + HDIM + d];

    float acc[8] = {0.f, 0.f, 0.f, 0.f, 0.f, 0.f, 0.f, 0.f};
    for (int k4 = 0; k4 < IN_DIM / 4; ++k4) {
        float w0 = sW[(k4 * 4 + 0) * OUT_DIM + lane];   // stride-1 b32: 2-way alias, free
        float w1 = sW[(k4 * 4 + 1) * OUT_DIM + lane];
        float w2 = sW[(k4 * 4 + 2) * OUT_DIM + lane];
        float w3 = sW[(k4 * 4 + 3) * OUT_DIM + lane];
        #pragma unroll
        for (int j = 0; j < 8; ++j) {
            float4 a = sF4[(wave * 8 + j) * (IN_DIM / 4) + k4];   // wave-uniform -> broadcast
            acc[j] = fmaf(a.x, w0, fmaf(a.y, w1, fmaf(a.z, w2, fmaf(a.w, w3, acc[j]))));
        }
    }

    float mAloc = -INFINITY, mDloc = -INFINITY;
    #pragma unroll
    for (int j = 0; j < 8; ++j) {
        int row = row0 + wave * 8 + j;
        bool ok = row < N;
        unsigned bits = __float_as_uint(acc[j]);
        unsigned r16 = (bits + 0x7FFFu + ((bits >> 16) & 1u)) >> 16;   // RNE bf16
        if (ok) h16[(size_t)row * OUT_DIM + lane] = (unsigned short)r16;
        float v1 = acc[j] * aw_s;
        float v2 = acc[j] * aw_d;
        #pragma unroll
        for (int off = 1; off < HDIM; off <<= 1) {
            v1 += __shfl_xor(v1, off, 64);
            v2 += __shfl_xor(v2, off, 64);
        }
        if (ok) {
            if (d == 0) {
                asrc[(size_t)row * NHEAD + head] = v1;
                adst[(size_t)row * NHEAD + head] = v2;
            }
            mAloc = fmaxf(mAloc, v1);
            mDloc = fmaxf(mDloc, v2);
        }
    }
    if (d == 0) { redA[wave][head] = mAloc; redD[wave][head] = mDloc; }
    __syncthreads();
    if (t < NHEAD) {
        float a = redA[0][t], dd = redD[0][t];
        for (int w = 1; w < 8; ++w) { a = fmaxf(a, redA[w][t]); dd = fmaxf(dd, redD[w][t]); }
        atomicMaxF(&mAD[t], a);
        atomicMaxF(&mAD[NHEAD + t], dd);
    }
}

// K5: per-dst-node softmax + weighted bf16-h gather, global shift B.
// One wave per node; lane = output column; 4-way unrolled independent gathers.
__global__ void k_fused(const int* __restrict__ cursor, const int* __restrict__ bsum,
                        const int* __restrict__ csr,
                        const float* __restrict__ asrc, const float* __restrict__ adst,
                        const float* __restrict__ mAD, const unsigned short* __restrict__ h16,
                        float* __restrict__ out, int nN) {
    int node = blockIdx.x * 4 + (threadIdx.x >> 6);
    if (node >= nN) return;
    int lane = threadIdx.x & 63;
    int head = lane >> 4;
    // after k_fill, cursor[d] = block-local inclusive end; global = + bsum[d>>10]
    int start = (node == 0) ? 0 : cursor[node - 1] + bsum[(node - 1) >> 10];
    int end = cursor[node] + bsum[node >> 10];
    float ad = adst[node * 4 + head];
    float B = lrelu(mAD[head] + mAD[4 + head]);
    float acc0 = 0.f, acc1 = 0.f, acc2 = 0.f, acc3 = 0.f;
    float l0 = 0.f, l1 = 0.f, l2 = 0.f, l3 = 0.f;
    for (int e = start; e < end; e += 4) {
        int n = end - e;
        int e1 = n > 1 ? e + 1 : e;
        int e2 = n > 2 ? e + 2 : e;
        int e3 = n > 3 ? e + 3 : e;
        int s0 = csr[e], s1 = csr[e1], s2 = csr[e2], s3 = csr[e3];
        float av0 = asrc[s0 * 4 + head];
        float av1 = asrc[s1 * 4 + head];
        float av2 = asrc[s2 * 4 + head];
        float av3 = asrc[s3 * 4 + head];
        float hv0 = bf16_to_f(h16[(size_t)s0 * OUT_DIM + lane]);
        float hv1 = bf16_to_f(h16[(size_t)s1 * OUT_DIM + lane]);
        float hv2 = bf16_to_f(h16[(size_t)s2 * OUT_DIM + lane]);
        float hv3 = bf16_to_f(h16[(size_t)s3 * OUT_DIM + lane]);
        float p0 = __expf(lrelu(av0 + ad) - B);
        float p1 = __expf(lrelu(av1 + ad) - B);
        float p2 = __expf(lrelu(av2 + ad) - B);
        float p3 = __expf(lrelu(av3 + ad) - B);
        p1 = (n > 1) ? p1 : 0.f;
        p2 = (n > 2) ? p2 : 0.f;
        p3 = (n > 3) ? p3 : 0.f;
        acc0 += p0 * hv0; l0 += p0;
        acc1 += p1 * hv1; l1 += p1;
        acc2 += p2 * hv2; l2 += p2;
        acc3 += p3 * hv3; l3 += p3;
    }
    float accs = (acc0 + acc1) + (acc2 + acc3);
    float ls = (l0 + l1) + (l2 + l3);
    out[(size_t)node * OUT_DIM + lane] = (end > start) ? accs / ls : 0.f;
}

extern "C" void kernel_launch(void* const* d_in, const int* in_sizes, int n_in,
                              void* d_out, int out_size, void* d_ws, size_t ws_size,
                              hipStream_t stream) {
    const float* feat   = (const float*)d_in[0];
    const int*   src    = (const int*)  d_in[1];
    const int*   dst    = (const int*)  d_in[2];
    const float* gumbel = (const float*)d_in[3];
    const float* logits = (const float*)d_in[4];
    const float* W      = (const float*)d_in[5];
    const float* attn_w = (const float*)d_in[6];
    float* out = (float*)d_out;

    int N = in_sizes[0] / IN_DIM;
    int E = in_sizes[1];
    int nb = (N + 1023) / 1024;

    float* ws     = (float*)d_ws;
    float* asrc   = ws;                                  // N*4
    float* adst   = asrc + (size_t)N * NHEAD;            // N*4
    float* mAD    = adst + (size_t)N * NHEAD;            // 8
    int*   deg    = (int*)(mAD + 8);                     // N
    int*   cursor = deg + N;                             // N
    int*   bsum   = cursor + N;                          // 256
    int*   csr    = bsum + 256;                          // E
    unsigned short* h16 = (unsigned short*)(csr + E);    // N*64 bf16

    hipMemsetAsync(deg, 0, (size_t)N * sizeof(int), stream);
    hipMemsetAsync(mAD, 0xFF, 8 * sizeof(float), stream);   // acts as -inf for atomicMaxF
    k_hist<<<(E + 255) / 256, 256, 0, stream>>>(dst, deg, E);
    k_scan1<<<nb, 256, 0, stream>>>(deg, cursor, bsum, N);
    k_scan2<<<1, 256, 0, stream>>>(bsum, nb);
    k_fill<<<(E + 255) / 256, 256, 0, stream>>>(src, dst, cursor, bsum, csr, E);
    k_gemm<<<(N + GR - 1) / GR, 512, 0, stream>>>(feat, W, logits, gumbel, attn_w,
                                                  h16, asrc, adst, mAD, N);
    k_fused<<<(N + 3) / 4, 256, 0, stream>>>(cursor, bsum, csr, asrc, adst, mAD, h16, out, N);
}

// Round 8
// 390.391 us; speedup vs baseline: 1.8783x; 1.1416x over previous
//
#include <hip/hip_runtime.h>
#include <hip/hip_bf16.h>
#include <math.h>

#define IN_DIM 128
#define OUT_DIM 64
#define NHEAD 4
#define HDIM 16
#define TEMP_INV 2.0f
#define NEG_SLOPE 0.01f
#define GR 64            // rows per gemm block
#define NFILL 2048       // grid for fillgemm (>= ceil(N/GR))

__device__ inline float lrelu(float x) { return x >= 0.f ? x : NEG_SLOPE * x; }

// mAD initialized to 0xFFFFFFFF (acts as -inf: int max vs -1; uint min vs UINT_MAX)
__device__ inline void atomicMaxF(float* addr, float v) {
    if (v >= 0.f) atomicMax((int*)addr, __float_as_int(v));
    else          atomicMin((unsigned int*)addr, __float_as_uint(v));
}

__device__ inline float bf16_to_f(unsigned short u) {
    return __uint_as_float(((unsigned)u) << 16);
}

// K1: histogram of dst -> deg; block 0 also inits mAD (read 2 dispatches later)
__global__ void k_hist(const int* __restrict__ dst, int* __restrict__ deg,
                       unsigned* __restrict__ mAD_bits, int nE) {
    if (blockIdx.x == 0 && threadIdx.x < 8) mAD_bits[threadIdx.x] = 0xFF800000u;
    int e = blockIdx.x * blockDim.x + threadIdx.x;
    if (e < nE) atomicAdd(&deg[dst[e]], 1);
}

// K2: per-block local exclusive scan; LAST block (ticket) also scans block sums.
// cursor[i] = block-local exclusive prefix; bsum[b] = exclusive block base (after).
__global__ void k_scan12(const int* __restrict__ deg, int* __restrict__ cursor,
                         int* __restrict__ bsum, int* __restrict__ flag, int n, int nb) {
    __shared__ int wsum[4];
    __shared__ int amLast;
    int t = threadIdx.x, lane = t & 63, wid = t >> 6;
    int i0 = blockIdx.x * 1024 + t * 4;
    int a0 = (i0 + 0 < n) ? deg[i0 + 0] : 0;
    int a1 = (i0 + 1 < n) ? deg[i0 + 1] : 0;
    int a2 = (i0 + 2 < n) ? deg[i0 + 2] : 0;
    int a3 = (i0 + 3 < n) ? deg[i0 + 3] : 0;
    int s = a0 + a1 + a2 + a3;
    int x = s;
    #pragma unroll
    for (int off = 1; off < 64; off <<= 1) {
        int y = __shfl_up(x, off, 64);
        if (lane >= off) x += y;
    }
    if (lane == 63) wsum[wid] = x;
    __syncthreads();
    int wbase = 0;
    for (int w = 0; w < wid; ++w) wbase += wsum[w];
    int excl = wbase + x - s;
    if (i0 + 0 < n) cursor[i0 + 0] = excl;
    if (i0 + 1 < n) cursor[i0 + 1] = excl + a0;
    if (i0 + 2 < n) cursor[i0 + 2] = excl + a0 + a1;
    if (i0 + 3 < n) cursor[i0 + 3] = excl + a0 + a1 + a2;
    if (t == 255) bsum[blockIdx.x] = wbase + x;   // block total (unscanned)

    // ---- last-block-done: scan bsum[0..nb) exclusive ----
    __threadfence();
    if (t == 0) amLast = (atomicAdd(flag, 1) == nb - 1);
    __syncthreads();
    if (!amLast) return;
    __threadfence();                               // acquire other blocks' bsum writes
    int v = (t < nb) ? bsum[t] : 0;
    int x2 = v;
    #pragma unroll
    for (int off = 1; off < 64; off <<= 1) {
        int y = __shfl_up(x2, off, 64);
        if (lane >= off) x2 += y;
    }
    if (lane == 63) wsum[wid] = x2;
    __syncthreads();
    int wbase2 = 0;
    for (int w = 0; w < wid; ++w) wbase2 += wsum[w];
    if (t < nb) bsum[t] = wbase2 + x2 - v;         // exclusive
}

// K3: fused fill + gemm. Blocks < NGEMM first compute a 64-row gemm tile
// (h16 bf16, asrc/adst, mAD); then ALL blocks grid-stride the CSR fill.
// Fill is latency-bound (16x scatter write-amp, VALUBusy 0.4%) -> hides under gemm.
__global__ __launch_bounds__(512) void k_fillgemm(
        const float* __restrict__ feat, const float* __restrict__ W,
        const float* __restrict__ logits, const float* __restrict__ gumbel,
        const float* __restrict__ attn_w, const int* __restrict__ src,
        const int* __restrict__ dst, int* __restrict__ cursor,
        const int* __restrict__ bsum, int* __restrict__ csr,
        unsigned short* __restrict__ h16, float* __restrict__ asrc,
        float* __restrict__ adst, float* __restrict__ mAD,
        int N, int E, int nGemm) {
    __shared__ float sW[IN_DIM * OUT_DIM];   // 32 KB (masked W)
    __shared__ float sF[GR * IN_DIM];        // 32 KB
    __shared__ float sMask[IN_DIM];
    __shared__ float sA[NHEAD * 2 * HDIM];
    __shared__ float redA[8][NHEAD], redD[8][NHEAD];

    int t = threadIdx.x;

    if (blockIdx.x < (unsigned)nGemm) {
        int row0 = blockIdx.x * GR;

        // ---- mask = softmax((logits+gumbel)/TEMP), in-block ----
        if (t < IN_DIM) sMask[t] = (logits[t] + gumbel[t]) * TEMP_INV;
        if (t < NHEAD * 2 * HDIM) sA[t] = attn_w[t];
        __syncthreads();
        float v = 0.f, ex = 0.f;
        if (t < IN_DIM) {
            v = sMask[t];
            float mx = -INFINITY;
            for (int i = 0; i < IN_DIM; ++i) mx = fmaxf(mx, sMask[i]);
            ex = __expf(v - mx);
        }
        __syncthreads();
        if (t < IN_DIM) sMask[t] = ex;
        __syncthreads();
        float sum = 0.f;
        if (t < IN_DIM) for (int i = 0; i < IN_DIM; ++i) sum += sMask[i];
        __syncthreads();
        if (t < IN_DIM) sMask[t] = ex / sum;
        __syncthreads();

        // ---- stage masked W and feat tile ----
        const float4* W4 = (const float4*)W;
        float4* sW4 = (float4*)sW;
        for (int i = t; i < IN_DIM * OUT_DIM / 4; i += 512) {
            float4 w = W4[i];
            float m = sMask[i >> 4];
            sW4[i] = make_float4(w.x * m, w.y * m, w.z * m, w.w * m);
        }
        const float4* feat4 = (const float4*)feat;
        float4* sF4 = (float4*)sF;
        int totF4 = N * (IN_DIM / 4);
        for (int i = t; i < GR * IN_DIM / 4; i += 512) {
            int g = row0 * (IN_DIM / 4) + i;
            sF4[i] = (g < totF4) ? feat4[g] : make_float4(0.f, 0.f, 0.f, 0.f);
        }
        __syncthreads();

        int wave = t >> 6, lane = t & 63;
        int head = lane >> 4, d = lane & 15;
        float aw_s = sA[head * 2 * HDIM + d];
        float aw_d = sA[head * 2 * HDIM + HDIM + d];

        float acc[8] = {0.f, 0.f, 0.f, 0.f, 0.f, 0.f, 0.f, 0.f};
        for (int k4 = 0; k4 < IN_DIM / 4; ++k4) {
            float w0 = sW[(k4 * 4 + 0) * OUT_DIM + lane];
            float w1 = sW[(k4 * 4 + 1) * OUT_DIM + lane];
            float w2 = sW[(k4 * 4 + 2) * OUT_DIM + lane];
            float w3 = sW[(k4 * 4 + 3) * OUT_DIM + lane];
            #pragma unroll
            for (int j = 0; j < 8; ++j) {
                float4 a = sF4[(wave * 8 + j) * (IN_DIM / 4) + k4];
                acc[j] = fmaf(a.x, w0, fmaf(a.y, w1, fmaf(a.z, w2, fmaf(a.w, w3, acc[j]))));
            }
        }

        float mAloc = -INFINITY, mDloc = -INFINITY;
        #pragma unroll
        for (int j = 0; j < 8; ++j) {
            int row = row0 + wave * 8 + j;
            bool ok = row < N;
            unsigned bits = __float_as_uint(acc[j]);
            unsigned r16 = (bits + 0x7FFFu + ((bits >> 16) & 1u)) >> 16;   // RNE bf16
            if (ok) h16[(size_t)row * OUT_DIM + lane] = (unsigned short)r16;
            float v1 = acc[j] * aw_s;
            float v2 = acc[j] * aw_d;
            #pragma unroll
            for (int off = 1; off < HDIM; off <<= 1) {
                v1 += __shfl_xor(v1, off, 64);
                v2 += __shfl_xor(v2, off, 64);
            }
            if (ok) {
                if (d == 0) {
                    asrc[(size_t)row * NHEAD + head] = v1;
                    adst[(size_t)row * NHEAD + head] = v2;
                }
                mAloc = fmaxf(mAloc, v1);
                mDloc = fmaxf(mDloc, v2);
            }
        }
        if (d == 0) { redA[wave][head] = mAloc; redD[wave][head] = mDloc; }
        __syncthreads();
        if (t < NHEAD) {
            float a = redA[0][t], dd = redD[0][t];
            for (int w = 1; w < 8; ++w) { a = fmaxf(a, redA[w][t]); dd = fmaxf(dd, redD[w][t]); }
            atomicMaxF(&mAD[t], a);
            atomicMaxF(&mAD[NHEAD + t], dd);
        }
    }

    // ---- fill slice (all blocks) ----
    int stride = gridDim.x * blockDim.x;
    for (int e = blockIdx.x * blockDim.x + t; e < E; e += stride) {
        int d = dst[e];
        int pos = atomicAdd(&cursor[d], 1) + bsum[d >> 10];
        csr[pos] = src[e];
    }
}

// K4: per-dst-node softmax + weighted bf16-h gather, global shift B.
// One wave per node; lane = output column; 8-wide unrolled independent gathers.
__global__ void k_fused(const int* __restrict__ cursor, const int* __restrict__ bsum,
                        const int* __restrict__ csr,
                        const float* __restrict__ asrc, const float* __restrict__ adst,
                        const float* __restrict__ mAD, const unsigned short* __restrict__ h16,
                        float* __restrict__ out, int nN) {
    int node = blockIdx.x * 4 + (threadIdx.x >> 6);
    if (node >= nN) return;
    int lane = threadIdx.x & 63;
    int head = lane >> 4;
    // after fill, cursor[d] = local inclusive end; global = + bsum[d>>10]
    int start = (node == 0) ? 0 : cursor[node - 1] + bsum[(node - 1) >> 10];
    int end = cursor[node] + bsum[node >> 10];
    float ad = adst[node * 4 + head];
    float B = lrelu(mAD[head] + mAD[4 + head]);
    float acc[8], l[8];
    #pragma unroll
    for (int j = 0; j < 8; ++j) { acc[j] = 0.f; l[j] = 0.f; }
    for (int e0 = start; e0 < end; e0 += 8) {
        int nrem = end - e0;
        int s[8]; float p[8]; float hv[8];
        #pragma unroll
        for (int j = 0; j < 8; ++j) {
            int ee = (j < nrem) ? e0 + j : e0;
            s[j] = csr[ee];
        }
        #pragma unroll
        for (int j = 0; j < 8; ++j)
            hv[j] = bf16_to_f(h16[(size_t)s[j] * OUT_DIM + lane]);
        #pragma unroll
        for (int j = 0; j < 8; ++j) {
            float av = asrc[s[j] * 4 + head];
            float pj = __expf(lrelu(av + ad) - B);
            p[j] = (j < nrem) ? pj : 0.f;
        }
        #pragma unroll
        for (int j = 0; j < 8; ++j) { acc[j] += p[j] * hv[j]; l[j] += p[j]; }
    }
    float accs = ((acc[0] + acc[1]) + (acc[2] + acc[3])) + ((acc[4] + acc[5]) + (acc[6] + acc[7]));
    float ls = ((l[0] + l[1]) + (l[2] + l[3])) + ((l[4] + l[5]) + (l[6] + l[7]));
    out[(size_t)node * OUT_DIM + lane] = (end > start) ? accs / ls : 0.f;
}

extern "C" void kernel_launch(void* const* d_in, const int* in_sizes, int n_in,
                              void* d_out, int out_size, void* d_ws, size_t ws_size,
                              hipStream_t stream) {
    const float* feat   = (const float*)d_in[0];
    const int*   src    = (const int*)  d_in[1];
    const int*   dst    = (const int*)  d_in[2];
    const float* gumbel = (const float*)d_in[3];
    const float* logits = (const float*)d_in[4];
    const float* W      = (const float*)d_in[5];
    const float* attn_w = (const float*)d_in[6];
    float* out = (float*)d_out;

    int N = in_sizes[0] / IN_DIM;
    int E = in_sizes[1];
    int nb = (N + 1023) / 1024;
    int nGemm = (N + GR - 1) / GR;
    int grid = NFILL > nGemm ? NFILL : nGemm;

    float* ws     = (float*)d_ws;
    float* asrc   = ws;                                  // N*4
    float* adst   = asrc + (size_t)N * NHEAD;            // N*4
    float* mAD    = adst + (size_t)N * NHEAD;            // 8
    int*   deg    = (int*)(mAD + 8);                     // N
    int*   flag   = deg + N;                             // 1 (zeroed with deg)
    int*   cursor = flag + 1;                            // N
    int*   bsum   = cursor + N;                          // 256
    int*   csr    = bsum + 256;                          // E
    unsigned short* h16 = (unsigned short*)(csr + E);    // N*64 bf16

    hipMemsetAsync(deg, 0, (size_t)(N + 1) * sizeof(int), stream);   // deg + flag
    k_hist<<<(E + 255) / 256, 256, 0, stream>>>(dst, deg, (unsigned*)mAD, E);
    k_scan12<<<nb, 256, 0, stream>>>(deg, cursor, bsum, flag, N, nb);
    k_fillgemm<<<grid, 512, 0, stream>>>(feat, W, logits, gumbel, attn_w, src, dst,
                                         cursor, bsum, csr, h16, asrc, adst, mAD,
                                         N, E, nGemm);
    k_fused<<<(N + 3) / 4, 256, 0, stream>>>(cursor, bsum, csr, asrc, adst, mAD,
                                             h16, out, N);
}